// Round 9
// baseline (185.544 us; speedup 1.0000x reference)
//
#include <hip/hip_runtime.h>
#include <math.h>

#define D_MODEL 512
#define N_SEQ   2048
#define H       8
#define DK      64

typedef __attribute__((ext_vector_type(8)))  short bf16x8;
typedef __attribute__((ext_vector_type(4)))  float f32x4;
typedef __attribute__((ext_vector_type(16))) float f32x16;

__device__ __forceinline__ unsigned short f2b(float f) {
    unsigned int u = __float_as_uint(f);
    u += 0x7FFF + ((u >> 16) & 1);          // round-to-nearest-even
    return (unsigned short)(u >> 16);
}

__device__ __forceinline__ unsigned int pack2(float lo, float hi) {
#if __has_builtin(__builtin_amdgcn_cvt_pk_bf16_f32)
    typedef __attribute__((ext_vector_type(2))) short bf16x2;
    bf16x2 p = __builtin_amdgcn_cvt_pk_bf16_f32(lo, hi);
    return (unsigned int)(unsigned short)p[0] |
           ((unsigned int)(unsigned short)p[1] << 16);
#else
    return (unsigned int)f2b(lo) | ((unsigned int)f2b(hi) << 16);
#endif
}

__device__ __forceinline__ float fexp2(float x) {
#if __has_builtin(__builtin_amdgcn_exp2f)
    return __builtin_amdgcn_exp2f(x);
#else
    return __expf(x * 0.6931471805599453f);
#endif
}

#define SC2 0.18033688011112042f    // (1/sqrt(64)) * log2(e), folded into Q

// ---------------------------------------------------------------------------
// fp32 -> bf16 elementwise (8 elems/thread) — keeps the pack VALU out of the
// QKV GEMM's hot loop.
// ---------------------------------------------------------------------------
__global__ void convert_bf16(const float* __restrict__ in,
                             unsigned short* __restrict__ out)
{
    const int i = (blockIdx.x * 256 + threadIdx.x) * 8;
    float4 a = *(const float4*)(in + i);
    float4 b = *(const float4*)(in + i + 4);
    unsigned int w[4];
    w[0] = pack2(a.x, a.y); w[1] = pack2(a.z, a.w);
    w[2] = pack2(b.x, b.y); w[3] = pack2(b.z, b.w);
    *(bf16x8*)(out + i) = *(bf16x8*)w;
}

// ---------------------------------------------------------------------------
// All four W[512,512] fp32 -> Wt[n][k] bf16, one launch (z picks the matrix)
// ---------------------------------------------------------------------------
__global__ void transpose_all(
    const float* __restrict__ W0, const float* __restrict__ W1,
    const float* __restrict__ W2, const float* __restrict__ W3,
    unsigned short* __restrict__ T0, unsigned short* __restrict__ T1,
    unsigned short* __restrict__ T2, unsigned short* __restrict__ T3)
{
    const float* W; unsigned short* Wt;
    if      (blockIdx.z == 0) { W = W0; Wt = T0; }
    else if (blockIdx.z == 1) { W = W1; Wt = T1; }
    else if (blockIdx.z == 2) { W = W2; Wt = T2; }
    else                      { W = W3; Wt = T3; }

    __shared__ float t[32][33];
    const int tx = threadIdx.x, ty = threadIdx.y;
    const int x = blockIdx.x * 32 + tx;
    const int y0 = blockIdx.y * 32;
    for (int i = ty; i < 32; i += 8)
        t[i][tx] = W[(size_t)(y0 + i) * D_MODEL + x];
    __syncthreads();
    const int ox = blockIdx.y * 32 + tx;
    const int oy0 = blockIdx.x * 32;
    for (int i = ty; i < 32; i += 8)
        Wt[(size_t)(oy0 + i) * D_MODEL + ox] = f2b(t[tx][i]);
}

// ---------------------------------------------------------------------------
// QKV projection GEMM: 128x64 tile, grid (8, 64, 3) = 1536 blocks (6/CU
// worth of blocks; 4 resident).  A = x bf16 [M,512]; B = Wt[n][k].
// Q/K (swap operands): C rows = d, cols = tokens -> packed d-contiguous
// ushort4 stores to [B,H,N,DK].  V: C rows = tokens -> token-packed stores
// to V^T [B,H,DK,N].  Q epilogue scales by SC2.
// ---------------------------------------------------------------------------
__global__ __launch_bounds__(256, 4) void gemm_qkv(
    const unsigned short* __restrict__ xb,
    const unsigned short* __restrict__ Wtq,
    const unsigned short* __restrict__ Wtk,
    const unsigned short* __restrict__ Wtv,
    const float* __restrict__ bq, const float* __restrict__ bk,
    const float* __restrict__ bv,
    unsigned short* __restrict__ Qb, unsigned short* __restrict__ Kb,
    unsigned short* __restrict__ Vtb)
{
    __shared__ unsigned short As[128][72];
    __shared__ unsigned short Bs[64][72];

    const unsigned short* Wt; const float* bias; unsigned short* out; int isV;
    float sc;
    if (blockIdx.z == 0)      { Wt = Wtq; bias = bq; out = Qb;  isV = 0; sc = SC2; }
    else if (blockIdx.z == 1) { Wt = Wtk; bias = bk; out = Kb;  isV = 0; sc = 1.0f; }
    else                      { Wt = Wtv; bias = bv; out = Vtb; isV = 1; sc = 1.0f; }

    const int tid  = threadIdx.x;
    const int lane = tid & 63, wave = tid >> 6;
    const int m0 = blockIdx.y * 128, n0 = blockIdx.x * 64;
    const int wm = (wave & 1) * 64, wn = (wave >> 1) * 32;
    const int cn = lane & 15, g = lane >> 4;

    const int arow = tid >> 1, acol = (tid & 1) * 32;
    const int brow = tid >> 2, bcol = (tid & 3) * 16;
    const unsigned short* Ag = xb + (size_t)(m0 + arow) * D_MODEL + acol;
    const unsigned short* Bg = Wt + (size_t)(n0 + brow) * D_MODEL + bcol;

    f32x4 acc[4][2];
    #pragma unroll
    for (int i = 0; i < 4; ++i)
        #pragma unroll
        for (int j = 0; j < 2; ++j)
            acc[i][j] = (f32x4){0.f, 0.f, 0.f, 0.f};

    for (int k0 = 0; k0 < D_MODEL; k0 += 64) {
        bf16x8 av[4], bv2[2];
        #pragma unroll
        for (int q = 0; q < 4; ++q) av[q] = *(const bf16x8*)(Ag + k0 + q * 8);
        #pragma unroll
        for (int q = 0; q < 2; ++q) bv2[q] = *(const bf16x8*)(Bg + k0 + q * 8);
        __syncthreads();
        #pragma unroll
        for (int q = 0; q < 4; ++q) *(bf16x8*)&As[arow][acol + q * 8] = av[q];
        #pragma unroll
        for (int q = 0; q < 2; ++q) *(bf16x8*)&Bs[brow][bcol + q * 8] = bv2[q];
        __syncthreads();

        #pragma unroll
        for (int ks = 0; ks < 2; ++ks) {
            bf16x8 af[4], bf[2];
            #pragma unroll
            for (int i = 0; i < 4; ++i)
                af[i] = *(const bf16x8*)&As[wm + i * 16 + cn][ks * 32 + g * 8];
            #pragma unroll
            for (int j = 0; j < 2; ++j)
                bf[j] = *(const bf16x8*)&Bs[wn + j * 16 + cn][ks * 32 + g * 8];
            if (!isV) {
                #pragma unroll
                for (int i = 0; i < 4; ++i)
                    #pragma unroll
                    for (int j = 0; j < 2; ++j)
                        acc[i][j] = __builtin_amdgcn_mfma_f32_16x16x32_bf16(
                            bf[j], af[i], acc[i][j], 0, 0, 0);
            } else {
                #pragma unroll
                for (int i = 0; i < 4; ++i)
                    #pragma unroll
                    for (int j = 0; j < 2; ++j)
                        acc[i][j] = __builtin_amdgcn_mfma_f32_16x16x32_bf16(
                            af[i], bf[j], acc[i][j], 0, 0, 0);
            }
        }
    }

    if (!isV) {        // Q/K: rows = d, cols = tokens; [B,H,N,DK] bf16
        #pragma unroll
        for (int j = 0; j < 2; ++j) {
            const int dbase = n0 + wn + j * 16 + g * 4;
            const int hh = dbase >> 6, dd = dbase & 63;
            float4 bb = *(const float4*)&bias[dbase];
            #pragma unroll
            for (int i = 0; i < 4; ++i) {
                const int tt = m0 + wm + i * 16 + cn;
                const int bi = tt >> 11, tok = tt & (N_SEQ - 1);
                ushort4 pk;
                pk.x = f2b((acc[i][j][0] + bb.x) * sc);
                pk.y = f2b((acc[i][j][1] + bb.y) * sc);
                pk.z = f2b((acc[i][j][2] + bb.z) * sc);
                pk.w = f2b((acc[i][j][3] + bb.w) * sc);
                *(ushort4*)(out + (((size_t)bi * H + hh) * N_SEQ + tok) * DK + dd) = pk;
            }
        }
    } else {           // V^T [B,H,DK,N]: rows = tokens, cols = d
        #pragma unroll
        for (int j = 0; j < 2; ++j) {
            const int n = n0 + wn + j * 16 + cn;
            const int hh = n >> 6, dd = n & 63;
            const float bb = bias[n];
            #pragma unroll
            for (int i = 0; i < 4; ++i) {
                const int m = m0 + wm + i * 16 + g * 4;
                const int bi = m >> 11, t = m & (N_SEQ - 1);
                ushort4 pk;
                pk.x = f2b(acc[i][j][0] + bb);
                pk.y = f2b(acc[i][j][1] + bb);
                pk.z = f2b(acc[i][j][2] + bb);
                pk.w = f2b(acc[i][j][3] + bb);
                *(ushort4*)(out + (((size_t)bi * H + hh) * DK + dd) * N_SEQ + t) = pk;
            }
        }
    }
}

// ---------------------------------------------------------------------------
// Output projection: 64x64 tile, 1024 blocks.  A bf16 [M,512], out fp32+bias.
// ---------------------------------------------------------------------------
__global__ __launch_bounds__(256, 4) void gemm_o(
    const unsigned short* __restrict__ A,
    const unsigned short* __restrict__ Wt,
    const float* __restrict__ bias, float* __restrict__ out)
{
    __shared__ unsigned short As[64][72];
    __shared__ unsigned short Bs[64][72];

    const int tid  = threadIdx.x;
    const int lane = tid & 63, wave = tid >> 6;
    const int m0 = blockIdx.y * 64, n0 = blockIdx.x * 64;
    const int wm = (wave & 1) * 32, wn = (wave >> 1) * 32;
    const int cn = lane & 15, g = lane >> 4;

    const int srow = tid >> 2;
    const int scol = (tid & 3) * 16;
    const unsigned short* Ag = A  + (size_t)(m0 + srow) * D_MODEL + scol;
    const unsigned short* Bg = Wt + (size_t)(n0 + srow) * D_MODEL + scol;

    f32x4 acc[2][2];
    #pragma unroll
    for (int i = 0; i < 2; ++i)
        #pragma unroll
        for (int j = 0; j < 2; ++j)
            acc[i][j] = (f32x4){0.f, 0.f, 0.f, 0.f};

    for (int k0 = 0; k0 < D_MODEL; k0 += 64) {
        bf16x8 av[2], bv[2];
        #pragma unroll
        for (int q = 0; q < 2; ++q) {
            av[q] = *(const bf16x8*)(Ag + k0 + q * 8);
            bv[q] = *(const bf16x8*)(Bg + k0 + q * 8);
        }
        __syncthreads();
        #pragma unroll
        for (int q = 0; q < 2; ++q) {
            *(bf16x8*)&As[srow][scol + q * 8] = av[q];
            *(bf16x8*)&Bs[srow][scol + q * 8] = bv[q];
        }
        __syncthreads();

        #pragma unroll
        for (int ks = 0; ks < 2; ++ks) {
            bf16x8 af[2], bf[2];
            #pragma unroll
            for (int i = 0; i < 2; ++i)
                af[i] = *(const bf16x8*)&As[wm + i * 16 + cn][ks * 32 + g * 8];
            #pragma unroll
            for (int j = 0; j < 2; ++j)
                bf[j] = *(const bf16x8*)&Bs[wn + j * 16 + cn][ks * 32 + g * 8];
            #pragma unroll
            for (int i = 0; i < 2; ++i)
                #pragma unroll
                for (int j = 0; j < 2; ++j)
                    acc[i][j] = __builtin_amdgcn_mfma_f32_16x16x32_bf16(
                        af[i], bf[j], acc[i][j], 0, 0, 0);
        }
    }

    #pragma unroll
    for (int j = 0; j < 2; ++j) {
        const int n = n0 + wn + j * 16 + cn;
        const float bb = bias[n];
        #pragma unroll
        for (int i = 0; i < 2; ++i)
            #pragma unroll
            for (int r = 0; r < 4; ++r) {
                const int m = m0 + wm + i * 16 + g * 4 + r;
                out[(size_t)m * D_MODEL + n] = acc[i][j][r] + bb;
            }
    }
}

// ---------------------------------------------------------------------------
// Flash attention, 32x32x16 MFMA, static softmax (Q pre-scaled by SC2).
// q-tile 64, 256 threads = 4 waves = 2 kv-halves x 2 q-strips -> grid 1024
// (4 blocks/CU).  1D grid with XCD swizzle: all 32 q-tiles of a (b,h) land
// on one XCD so K/V stay L2-resident.  Zero-shuffle P via sigma permutation;
// l via ones-A MFMA; kv-half partials combine through LDS.
// ---------------------------------------------------------------------------
__global__ __launch_bounds__(256, 4) void attn_mfma(
    const unsigned short* __restrict__ Q,
    const unsigned short* __restrict__ K,
    const unsigned short* __restrict__ Vt,
    unsigned short* __restrict__ ctx)
{
    __shared__ unsigned short SM[2][2][64][72];   // [kv-half][K|V][row][col]

    const int bid = blockIdx.x;
    const int qt = (bid >> 3) & 31;               // 32 q-tiles of 64
    const int bh = (bid & 7) * 4 + (bid >> 8);    // XCD-local (b,h) group
    const int b = bh >> 3, h = bh & 7;

    const int tid = threadIdx.x, lane = tid & 63, wave = tid >> 6;
    const int sp = wave >> 1;                 // kv half (compute)
    const int w4 = wave & 1;                  // q-strip
    const int lq = lane & 31, hf = lane >> 5;
    const int qs = qt * 64 + w4 * 32;

    const size_t hb = (size_t)b * H + h;
    const unsigned short* Qp = Q  + hb * N_SEQ * DK;
    const unsigned short* Kp = K  + hb * N_SEQ * DK;
    const unsigned short* Vp = Vt + hb * DK * N_SEQ;

    bf16x8 qf[4];
    #pragma unroll
    for (int kd = 0; kd < 4; ++kd)
        qf[kd] = *(const bf16x8*)(Qp + (size_t)(qs + lq) * DK + kd * 16 + hf * 8);

    f32x16 O[2], Ol;
    #pragma unroll
    for (int r = 0; r < 16; ++r) { O[0][r] = 0.f; O[1][r] = 0.f; Ol[r] = 0.f; }

    bf16x8 onesA;                             // A ones-frag: row m==0 only
    {
        const short v = (lq == 0) ? (short)0x3F80 : (short)0;
        #pragma unroll
        for (int j = 0; j < 8; ++j) onesA[j] = v;
    }

    // staging: threads 0-127 fill half 0, 128-255 fill half 1 (matches the
    // wave->sp compute mapping, so producer==consumer locality).
    const int sps = tid >> 7;
    const int tl = tid & 127;
    const int krow = tl >> 1, kcol = (tl & 1) * 32;
    unsigned short (*Kss)[72] = SM[sps][0];
    unsigned short (*Vss)[72] = SM[sps][1];
    unsigned short (*Ks)[72]  = SM[sp][0];
    unsigned short (*Vs)[72]  = SM[sp][1];

    for (int it = 0; it < 16; ++it) {
        const int j0 = sps * (N_SEQ / 2) + it * 64;
        bf16x8 kv[4], vv[4];
        #pragma unroll
        for (int q = 0; q < 4; ++q) {
            kv[q] = *(const bf16x8*)(Kp + (size_t)(j0 + krow) * DK + kcol + q * 8);
            vv[q] = *(const bf16x8*)(Vp + (size_t)krow * N_SEQ + j0 + kcol + q * 8);
        }
        // sigma per 16-col chunk: (q0,q2),(q1,q3)
        bf16x8 sw[4];
        {
            ushort4* v0 = (ushort4*)&vv[0]; ushort4* v1 = (ushort4*)&vv[1];
            ushort4* v2 = (ushort4*)&vv[2]; ushort4* v3 = (ushort4*)&vv[3];
            ushort4* s0 = (ushort4*)&sw[0]; ushort4* s1 = (ushort4*)&sw[1];
            ushort4* s2 = (ushort4*)&sw[2]; ushort4* s3 = (ushort4*)&sw[3];
            s0[0] = v0[0]; s0[1] = v1[0];
            s1[0] = v0[1]; s1[1] = v1[1];
            s2[0] = v2[0]; s2[1] = v3[0];
            s3[0] = v2[1]; s3[1] = v3[1];
        }
        __syncthreads();
        #pragma unroll
        for (int q = 0; q < 4; ++q) {
            *(bf16x8*)&Kss[krow][kcol + q * 8] = kv[q];
            *(bf16x8*)&Vss[krow][kcol + q * 8] = sw[q];
        }
        __syncthreads();

        // S^T[kv][q] (log2 domain)
        f32x16 s0, s1;
        #pragma unroll
        for (int r = 0; r < 16; ++r) { s0[r] = 0.f; s1[r] = 0.f; }
        #pragma unroll
        for (int kd = 0; kd < 4; ++kd) {
            bf16x8 a0 = *(const bf16x8*)&Ks[lq][kd * 16 + hf * 8];
            bf16x8 a1 = *(const bf16x8*)&Ks[32 + lq][kd * 16 + hf * 8];
            s0 = __builtin_amdgcn_mfma_f32_32x32x16_bf16(a0, qf[kd], s0, 0, 0, 0);
            s1 = __builtin_amdgcn_mfma_f32_32x32x16_bf16(a1, qf[kd], s1, 0, 0, 0);
        }

        // p = exp2(s); pk[c][p] = packed regs (4c+2p, 4c+2p+1) = kv quads
        unsigned int pk0[4][2], pk1[4][2];
        #pragma unroll
        for (int c = 0; c < 4; ++c)
            #pragma unroll
            for (int p = 0; p < 2; ++p) {
                pk0[c][p] = pack2(fexp2(s0[4 * c + 2 * p]),
                                  fexp2(s0[4 * c + 2 * p + 1]));
                pk1[c][p] = pack2(fexp2(s1[4 * c + 2 * p]),
                                  fexp2(s1[4 * c + 2 * p + 1]));
            }

        // O^T += V^T.P^T with sigma-permuted K axis: B-frag = own C quads
        #pragma unroll
        for (int ks = 0; ks < 4; ++ks) {
            const unsigned int (*src)[2] = (ks < 2) ? pk0 : pk1;
            const int c2 = (ks & 1) * 2;
            bf16x8 bp;
            unsigned int* bpu = (unsigned int*)&bp;
            bpu[0] = src[c2][0];     bpu[1] = src[c2][1];
            bpu[2] = src[c2 + 1][0]; bpu[3] = src[c2 + 1][1];
            bf16x8 va0 = *(const bf16x8*)&Vs[lq][ks * 16 + hf * 8];
            bf16x8 va1 = *(const bf16x8*)&Vs[32 + lq][ks * 16 + hf * 8];
            O[0] = __builtin_amdgcn_mfma_f32_32x32x16_bf16(va0, bp, O[0], 0, 0, 0);
            O[1] = __builtin_amdgcn_mfma_f32_32x32x16_bf16(va1, bp, O[1], 0, 0, 0);
            Ol   = __builtin_amdgcn_mfma_f32_32x32x16_bf16(onesA, bp, Ol, 0, 0, 0);
        }
    }

    // ---- combine the two kv-halves through LDS ----
    float* R    = (float*)&SM[0][0][0][0];    // [w4][64 d][32 q] fp32 = 16 KB
    float* Laux = R + 2 * 64 * 32;            // [w4][32 q]

    __syncthreads();                          // everyone done with tiles
    if (sp == 1) {
        #pragma unroll
        for (int dt = 0; dt < 2; ++dt)
            #pragma unroll
            for (int r = 0; r < 16; ++r) {
                const int d = (r & 3) + 8 * (r >> 2) + 4 * hf + 32 * dt;
                R[(w4 * 64 + d) * 32 + lq] = O[dt][r];
            }
        if (hf == 0) Laux[w4 * 32 + lq] = Ol[0];
    }
    __syncthreads();
    if (sp == 0) {
        #pragma unroll
        for (int dt = 0; dt < 2; ++dt)
            #pragma unroll
            for (int r = 0; r < 16; ++r) {
                const int d = (r & 3) + 8 * (r >> 2) + 4 * hf + 32 * dt;
                O[dt][r] += R[(w4 * 64 + d) * 32 + lq];
            }
        const float lsum = Ol[0] + Laux[w4 * 32 + lq];
        const float linv = 1.0f / __shfl(lsum, lq);

        unsigned short* ob = ctx + ((size_t)b * N_SEQ + qs + lq) * D_MODEL
                                 + h * DK + hf * 4;
        #pragma unroll
        for (int dt = 0; dt < 2; ++dt)
            #pragma unroll
            for (int c = 0; c < 4; ++c) {
                unsigned int w2[2];
                w2[0] = pack2(O[dt][4 * c + 0] * linv, O[dt][4 * c + 1] * linv);
                w2[1] = pack2(O[dt][4 * c + 2] * linv, O[dt][4 * c + 3] * linv);
                *(unsigned int*)(ob + dt * 32 + c * 8)     = w2[0];
                *(unsigned int*)(ob + dt * 32 + c * 8 + 2) = w2[1];
            }
    }
}

// ---------------------------------------------------------------------------
extern "C" void kernel_launch(void* const* d_in, const int* in_sizes, int n_in,
                              void* d_out, int out_size, void* d_ws, size_t ws_size,
                              hipStream_t stream)
{
    const float* x  = (const float*)d_in[0];
    const float* Wq = (const float*)d_in[1];
    const float* bq = (const float*)d_in[2];
    const float* Wk = (const float*)d_in[3];
    const float* bk = (const float*)d_in[4];
    const float* Wv = (const float*)d_in[5];
    const float* bv = (const float*)d_in[6];
    const float* Wo = (const float*)d_in[7];
    const float* bo = (const float*)d_in[8];
    float* out = (float*)d_out;

    const int M = in_sizes[0] / D_MODEL;        // 8192
    const size_t NX = (size_t)M * D_MODEL;
    const size_t NW = (size_t)D_MODEL * D_MODEL;

    unsigned short* xb  = (unsigned short*)d_ws;
    unsigned short* Wtq = xb + NX;
    unsigned short* Wtk = Wtq + NW;
    unsigned short* Wtv = Wtk + NW;
    unsigned short* Wto = Wtv + NW;
    unsigned short* Qb  = Wto + NW;
    unsigned short* Kb  = Qb + NX;
    unsigned short* Vtb = Kb + NX;
    unsigned short* ctx = Vtb + NX;

    convert_bf16<<<NX / (256 * 8), 256, 0, stream>>>(x, xb);
    transpose_all<<<dim3(16, 16, 4), dim3(32, 8), 0, stream>>>(
        Wq, Wk, Wv, Wo, Wtq, Wtk, Wtv, Wto);

    gemm_qkv<<<dim3(D_MODEL / 64, M / 128, 3), 256, 0, stream>>>(
        xb, Wtq, Wtk, Wtv, bq, bk, bv, Qb, Kb, Vtb);
    attn_mfma<<<1024, 256, 0, stream>>>(Qb, Kb, Vtb, ctx);
    gemm_o<<<dim3(D_MODEL / 64, M / 64), 256, 0, stream>>>(ctx, Wto, bo, out);
}

// Round 10
// 179.089 us; speedup vs baseline: 1.0360x; 1.0360x over previous
//
#include <hip/hip_runtime.h>
#include <math.h>

#define D_MODEL 512
#define N_SEQ   2048
#define H       8
#define DK      64

typedef __attribute__((ext_vector_type(8)))  short bf16x8;
typedef __attribute__((ext_vector_type(4)))  float f32x4;
typedef __attribute__((ext_vector_type(16))) float f32x16;

__device__ __forceinline__ unsigned short f2b(float f) {
    unsigned int u = __float_as_uint(f);
    u += 0x7FFF + ((u >> 16) & 1);          // round-to-nearest-even
    return (unsigned short)(u >> 16);
}

__device__ __forceinline__ unsigned int pack2(float lo, float hi) {
#if __has_builtin(__builtin_amdgcn_cvt_pk_bf16_f32)
    typedef __attribute__((ext_vector_type(2))) short bf16x2;
    bf16x2 p = __builtin_amdgcn_cvt_pk_bf16_f32(lo, hi);
    return (unsigned int)(unsigned short)p[0] |
           ((unsigned int)(unsigned short)p[1] << 16);
#else
    return (unsigned int)f2b(lo) | ((unsigned int)f2b(hi) << 16);
#endif
}

__device__ __forceinline__ float fexp2(float x) {
#if __has_builtin(__builtin_amdgcn_exp2f)
    return __builtin_amdgcn_exp2f(x);
#else
    return __expf(x * 0.6931471805599453f);
#endif
}

#define SC2 0.18033688011112042f    // (1/sqrt(64)) * log2(e), folded into Q

// ---------------------------------------------------------------------------
// fp32 -> bf16 elementwise (8 elems/thread)
// ---------------------------------------------------------------------------
__global__ void convert_bf16(const float* __restrict__ in,
                             unsigned short* __restrict__ out)
{
    const int i = (blockIdx.x * 256 + threadIdx.x) * 8;
    float4 a = *(const float4*)(in + i);
    float4 b = *(const float4*)(in + i + 4);
    unsigned int w[4];
    w[0] = pack2(a.x, a.y); w[1] = pack2(a.z, a.w);
    w[2] = pack2(b.x, b.y); w[3] = pack2(b.z, b.w);
    *(bf16x8*)(out + i) = *(bf16x8*)w;
}

// ---------------------------------------------------------------------------
// All four W[512,512] fp32 -> Wt[n][k] bf16, one launch (z picks the matrix)
// ---------------------------------------------------------------------------
__global__ void transpose_all(
    const float* __restrict__ W0, const float* __restrict__ W1,
    const float* __restrict__ W2, const float* __restrict__ W3,
    unsigned short* __restrict__ T0, unsigned short* __restrict__ T1,
    unsigned short* __restrict__ T2, unsigned short* __restrict__ T3)
{
    const float* W; unsigned short* Wt;
    if      (blockIdx.z == 0) { W = W0; Wt = T0; }
    else if (blockIdx.z == 1) { W = W1; Wt = T1; }
    else if (blockIdx.z == 2) { W = W2; Wt = T2; }
    else                      { W = W3; Wt = T3; }

    __shared__ float t[32][33];
    const int tx = threadIdx.x, ty = threadIdx.y;
    const int x = blockIdx.x * 32 + tx;
    const int y0 = blockIdx.y * 32;
    for (int i = ty; i < 32; i += 8)
        t[i][tx] = W[(size_t)(y0 + i) * D_MODEL + x];
    __syncthreads();
    const int ox = blockIdx.y * 32 + tx;
    const int oy0 = blockIdx.x * 32;
    for (int i = ty; i < 32; i += 8)
        Wt[(size_t)(oy0 + i) * D_MODEL + ox] = f2b(t[tx][i]);
}

// ---------------------------------------------------------------------------
// QKV projection GEMM: 128x64 tile, grid (8, 64, 3) = 1536 blocks.
// Q/K (swap operands): C rows = d, cols = tokens -> packed d-contiguous
// ushort4 stores to [B,H,N,DK].  V: token-packed stores to V^T [B,H,DK,N].
// Q epilogue scales by SC2.  (unchanged from r9 — measured winner)
// ---------------------------------------------------------------------------
__global__ __launch_bounds__(256, 4) void gemm_qkv(
    const unsigned short* __restrict__ xb,
    const unsigned short* __restrict__ Wtq,
    const unsigned short* __restrict__ Wtk,
    const unsigned short* __restrict__ Wtv,
    const float* __restrict__ bq, const float* __restrict__ bk,
    const float* __restrict__ bv,
    unsigned short* __restrict__ Qb, unsigned short* __restrict__ Kb,
    unsigned short* __restrict__ Vtb)
{
    __shared__ unsigned short As[128][72];
    __shared__ unsigned short Bs[64][72];

    const unsigned short* Wt; const float* bias; unsigned short* out; int isV;
    float sc;
    if (blockIdx.z == 0)      { Wt = Wtq; bias = bq; out = Qb;  isV = 0; sc = SC2; }
    else if (blockIdx.z == 1) { Wt = Wtk; bias = bk; out = Kb;  isV = 0; sc = 1.0f; }
    else                      { Wt = Wtv; bias = bv; out = Vtb; isV = 1; sc = 1.0f; }

    const int tid  = threadIdx.x;
    const int lane = tid & 63, wave = tid >> 6;
    const int m0 = blockIdx.y * 128, n0 = blockIdx.x * 64;
    const int wm = (wave & 1) * 64, wn = (wave >> 1) * 32;
    const int cn = lane & 15, g = lane >> 4;

    const int arow = tid >> 1, acol = (tid & 1) * 32;
    const int brow = tid >> 2, bcol = (tid & 3) * 16;
    const unsigned short* Ag = xb + (size_t)(m0 + arow) * D_MODEL + acol;
    const unsigned short* Bg = Wt + (size_t)(n0 + brow) * D_MODEL + bcol;

    f32x4 acc[4][2];
    #pragma unroll
    for (int i = 0; i < 4; ++i)
        #pragma unroll
        for (int j = 0; j < 2; ++j)
            acc[i][j] = (f32x4){0.f, 0.f, 0.f, 0.f};

    for (int k0 = 0; k0 < D_MODEL; k0 += 64) {
        bf16x8 av[4], bv2[2];
        #pragma unroll
        for (int q = 0; q < 4; ++q) av[q] = *(const bf16x8*)(Ag + k0 + q * 8);
        #pragma unroll
        for (int q = 0; q < 2; ++q) bv2[q] = *(const bf16x8*)(Bg + k0 + q * 8);
        __syncthreads();
        #pragma unroll
        for (int q = 0; q < 4; ++q) *(bf16x8*)&As[arow][acol + q * 8] = av[q];
        #pragma unroll
        for (int q = 0; q < 2; ++q) *(bf16x8*)&Bs[brow][bcol + q * 8] = bv2[q];
        __syncthreads();

        #pragma unroll
        for (int ks = 0; ks < 2; ++ks) {
            bf16x8 af[4], bf[2];
            #pragma unroll
            for (int i = 0; i < 4; ++i)
                af[i] = *(const bf16x8*)&As[wm + i * 16 + cn][ks * 32 + g * 8];
            #pragma unroll
            for (int j = 0; j < 2; ++j)
                bf[j] = *(const bf16x8*)&Bs[wn + j * 16 + cn][ks * 32 + g * 8];
            if (!isV) {
                #pragma unroll
                for (int i = 0; i < 4; ++i)
                    #pragma unroll
                    for (int j = 0; j < 2; ++j)
                        acc[i][j] = __builtin_amdgcn_mfma_f32_16x16x32_bf16(
                            bf[j], af[i], acc[i][j], 0, 0, 0);
            } else {
                #pragma unroll
                for (int i = 0; i < 4; ++i)
                    #pragma unroll
                    for (int j = 0; j < 2; ++j)
                        acc[i][j] = __builtin_amdgcn_mfma_f32_16x16x32_bf16(
                            af[i], bf[j], acc[i][j], 0, 0, 0);
            }
        }
    }

    if (!isV) {        // Q/K: rows = d, cols = tokens; [B,H,N,DK] bf16
        #pragma unroll
        for (int j = 0; j < 2; ++j) {
            const int dbase = n0 + wn + j * 16 + g * 4;
            const int hh = dbase >> 6, dd = dbase & 63;
            float4 bb = *(const float4*)&bias[dbase];
            #pragma unroll
            for (int i = 0; i < 4; ++i) {
                const int tt = m0 + wm + i * 16 + cn;
                const int bi = tt >> 11, tok = tt & (N_SEQ - 1);
                ushort4 pk;
                pk.x = f2b((acc[i][j][0] + bb.x) * sc);
                pk.y = f2b((acc[i][j][1] + bb.y) * sc);
                pk.z = f2b((acc[i][j][2] + bb.z) * sc);
                pk.w = f2b((acc[i][j][3] + bb.w) * sc);
                *(ushort4*)(out + (((size_t)bi * H + hh) * N_SEQ + tok) * DK + dd) = pk;
            }
        }
    } else {           // V^T [B,H,DK,N]: rows = tokens, cols = d
        #pragma unroll
        for (int j = 0; j < 2; ++j) {
            const int n = n0 + wn + j * 16 + cn;
            const int hh = n >> 6, dd = n & 63;
            const float bb = bias[n];
            #pragma unroll
            for (int i = 0; i < 4; ++i) {
                const int m = m0 + wm + i * 16 + g * 4;
                const int bi = m >> 11, t = m & (N_SEQ - 1);
                ushort4 pk;
                pk.x = f2b(acc[i][j][0] + bb);
                pk.y = f2b(acc[i][j][1] + bb);
                pk.z = f2b(acc[i][j][2] + bb);
                pk.w = f2b(acc[i][j][3] + bb);
                *(ushort4*)(out + (((size_t)bi * H + hh) * DK + dd) * N_SEQ + t) = pk;
            }
        }
    }
}

// ---------------------------------------------------------------------------
// Output projection: 64x64 tile, 1024 blocks.  (unchanged from r9)
// ---------------------------------------------------------------------------
__global__ __launch_bounds__(256, 4) void gemm_o(
    const unsigned short* __restrict__ A,
    const unsigned short* __restrict__ Wt,
    const float* __restrict__ bias, float* __restrict__ out)
{
    __shared__ unsigned short As[64][72];
    __shared__ unsigned short Bs[64][72];

    const int tid  = threadIdx.x;
    const int lane = tid & 63, wave = tid >> 6;
    const int m0 = blockIdx.y * 64, n0 = blockIdx.x * 64;
    const int wm = (wave & 1) * 32, wn = (wave >> 1) * 32;
    const int cn = lane & 15, g = lane >> 4;

    const int srow = tid >> 2;
    const int scol = (tid & 3) * 16;
    const unsigned short* Ag = A  + (size_t)(m0 + srow) * D_MODEL + scol;
    const unsigned short* Bg = Wt + (size_t)(n0 + srow) * D_MODEL + scol;

    f32x4 acc[2][2];
    #pragma unroll
    for (int i = 0; i < 2; ++i)
        #pragma unroll
        for (int j = 0; j < 2; ++j)
            acc[i][j] = (f32x4){0.f, 0.f, 0.f, 0.f};

    for (int k0 = 0; k0 < D_MODEL; k0 += 64) {
        bf16x8 av[2], bv[2];
        #pragma unroll
        for (int q = 0; q < 2; ++q) {
            av[q] = *(const bf16x8*)(Ag + k0 + q * 8);
            bv[q] = *(const bf16x8*)(Bg + k0 + q * 8);
        }
        __syncthreads();
        #pragma unroll
        for (int q = 0; q < 2; ++q) {
            *(bf16x8*)&As[srow][scol + q * 8] = av[q];
            *(bf16x8*)&Bs[srow][scol + q * 8] = bv[q];
        }
        __syncthreads();

        #pragma unroll
        for (int ks = 0; ks < 2; ++ks) {
            bf16x8 af[2], bf[2];
            #pragma unroll
            for (int i = 0; i < 2; ++i)
                af[i] = *(const bf16x8*)&As[wm + i * 16 + cn][ks * 32 + g * 8];
            #pragma unroll
            for (int j = 0; j < 2; ++j)
                bf[j] = *(const bf16x8*)&Bs[wn + j * 16 + cn][ks * 32 + g * 8];
            #pragma unroll
            for (int i = 0; i < 2; ++i)
                #pragma unroll
                for (int j = 0; j < 2; ++j)
                    acc[i][j] = __builtin_amdgcn_mfma_f32_16x16x32_bf16(
                        af[i], bf[j], acc[i][j], 0, 0, 0);
        }
    }

    #pragma unroll
    for (int j = 0; j < 2; ++j) {
        const int n = n0 + wn + j * 16 + cn;
        const float bb = bias[n];
        #pragma unroll
        for (int i = 0; i < 2; ++i)
            #pragma unroll
            for (int r = 0; r < 4; ++r) {
                const int m = m0 + wm + i * 16 + g * 4 + r;
                out[(size_t)m * D_MODEL + n] = acc[i][j][r] + bb;
            }
    }
}

// ---------------------------------------------------------------------------
// Flash attention, 32x32x16 MFMA, static softmax (Q pre-scaled by SC2).
// NEW: each wave owns TWO 32-q strips (64 q).  K/V fragments are read from
// LDS into registers ONCE per iter and reused for both strips -> LDS reads
// per MFMA halve (r9 counters: LDS pipe was ~51% of runtime).  Block = 4
// waves = 2 kv-halves x 2 strip-pairs -> q-tile 128, grid 512.
// Zero-shuffle P via sigma permutation; l via ones-A MFMA; kv-half partials
// combine through LDS.  XCD swizzle keeps each (b,h)'s K/V L2-resident.
// ---------------------------------------------------------------------------
__global__ __launch_bounds__(256, 2) void attn_mfma(
    const unsigned short* __restrict__ Q,
    const unsigned short* __restrict__ K,
    const unsigned short* __restrict__ Vt,
    unsigned short* __restrict__ ctx)
{
    __shared__ unsigned short SM[2][2][64][72];   // [kv-half][K|V][row][col]

    const int bid = blockIdx.x;                   // grid 512
    const int qt = (bid >> 3) & 15;               // 16 q-tiles of 128
    const int bh = (bid & 7) * 4 + (bid >> 7);    // XCD-local (b,h) group
    const int b = bh >> 3, h = bh & 7;

    const int tid = threadIdx.x, lane = tid & 63, wave = tid >> 6;
    const int sp = wave >> 1;                 // kv half (compute)
    const int w4 = wave & 1;                  // strip-pair within tile
    const int lq = lane & 31, hf = lane >> 5;
    const int qbase = qt * 128 + w4 * 64;

    const size_t hb = (size_t)b * H + h;
    const unsigned short* Qp = Q  + hb * N_SEQ * DK;
    const unsigned short* Kp = K  + hb * N_SEQ * DK;
    const unsigned short* Vp = Vt + hb * DK * N_SEQ;

    bf16x8 qf[2][4];
    #pragma unroll
    for (int u = 0; u < 2; ++u)
        #pragma unroll
        for (int kd = 0; kd < 4; ++kd)
            qf[u][kd] = *(const bf16x8*)(Qp +
                (size_t)(qbase + u * 32 + lq) * DK + kd * 16 + hf * 8);

    f32x16 O[2][2], Ol[2];
    #pragma unroll
    for (int u = 0; u < 2; ++u)
        #pragma unroll
        for (int r = 0; r < 16; ++r) {
            O[u][0][r] = 0.f; O[u][1][r] = 0.f; Ol[u][r] = 0.f;
        }

    bf16x8 onesA;                             // A ones-frag: row m==0 only
    {
        const short v = (lq == 0) ? (short)0x3F80 : (short)0;
        #pragma unroll
        for (int j = 0; j < 8; ++j) onesA[j] = v;
    }

    // staging: threads 0-127 fill half 0, 128-255 fill half 1
    const int sps = tid >> 7;
    const int tl = tid & 127;
    const int krow = tl >> 1, kcol = (tl & 1) * 32;
    unsigned short (*Kss)[72] = SM[sps][0];
    unsigned short (*Vss)[72] = SM[sps][1];
    unsigned short (*Ks)[72]  = SM[sp][0];
    unsigned short (*Vs)[72]  = SM[sp][1];

    for (int it = 0; it < 16; ++it) {
        const int j0 = sps * (N_SEQ / 2) + it * 64;
        bf16x8 kv[4], vv[4];
        #pragma unroll
        for (int q = 0; q < 4; ++q) {
            kv[q] = *(const bf16x8*)(Kp + (size_t)(j0 + krow) * DK + kcol + q * 8);
            vv[q] = *(const bf16x8*)(Vp + (size_t)krow * N_SEQ + j0 + kcol + q * 8);
        }
        // sigma per 16-col chunk: (q0,q2),(q1,q3)
        bf16x8 sw[4];
        {
            ushort4* v0 = (ushort4*)&vv[0]; ushort4* v1 = (ushort4*)&vv[1];
            ushort4* v2 = (ushort4*)&vv[2]; ushort4* v3 = (ushort4*)&vv[3];
            ushort4* s0 = (ushort4*)&sw[0]; ushort4* s1 = (ushort4*)&sw[1];
            ushort4* s2 = (ushort4*)&sw[2]; ushort4* s3 = (ushort4*)&sw[3];
            s0[0] = v0[0]; s0[1] = v1[0];
            s1[0] = v0[1]; s1[1] = v1[1];
            s2[0] = v2[0]; s2[1] = v3[0];
            s3[0] = v2[1]; s3[1] = v3[1];
        }
        __syncthreads();
        #pragma unroll
        for (int q = 0; q < 4; ++q) {
            *(bf16x8*)&Kss[krow][kcol + q * 8] = kv[q];
            *(bf16x8*)&Vss[krow][kcol + q * 8] = sw[q];
        }
        __syncthreads();

        // K-frags read ONCE, reused by both q-strips
        bf16x8 ka0[4], ka1[4];
        #pragma unroll
        for (int kd = 0; kd < 4; ++kd) {
            ka0[kd] = *(const bf16x8*)&Ks[lq][kd * 16 + hf * 8];
            ka1[kd] = *(const bf16x8*)&Ks[32 + lq][kd * 16 + hf * 8];
        }

        unsigned int pA[2][4][2], pB[2][4][2];
        #pragma unroll
        for (int u = 0; u < 2; ++u) {
            f32x16 s0, s1;
            #pragma unroll
            for (int r = 0; r < 16; ++r) { s0[r] = 0.f; s1[r] = 0.f; }
            #pragma unroll
            for (int kd = 0; kd < 4; ++kd) {
                s0 = __builtin_amdgcn_mfma_f32_32x32x16_bf16(ka0[kd], qf[u][kd], s0, 0, 0, 0);
                s1 = __builtin_amdgcn_mfma_f32_32x32x16_bf16(ka1[kd], qf[u][kd], s1, 0, 0, 0);
            }
            #pragma unroll
            for (int c = 0; c < 4; ++c)
                #pragma unroll
                for (int p = 0; p < 2; ++p) {
                    pA[u][c][p] = pack2(fexp2(s0[4 * c + 2 * p]),
                                        fexp2(s0[4 * c + 2 * p + 1]));
                    pB[u][c][p] = pack2(fexp2(s1[4 * c + 2 * p]),
                                        fexp2(s1[4 * c + 2 * p + 1]));
                }
        }

        // V-frags read ONCE, reused by both q-strips
        bf16x8 va0[4], va1[4];
        #pragma unroll
        for (int ks = 0; ks < 4; ++ks) {
            va0[ks] = *(const bf16x8*)&Vs[lq][ks * 16 + hf * 8];
            va1[ks] = *(const bf16x8*)&Vs[32 + lq][ks * 16 + hf * 8];
        }

        #pragma unroll
        for (int u = 0; u < 2; ++u)
            #pragma unroll
            for (int ks = 0; ks < 4; ++ks) {
                const unsigned int (*src)[2] = (ks < 2) ? pA[u] : pB[u];
                const int c2 = (ks & 1) * 2;
                bf16x8 bp;
                unsigned int* bpu = (unsigned int*)&bp;
                bpu[0] = src[c2][0];     bpu[1] = src[c2][1];
                bpu[2] = src[c2 + 1][0]; bpu[3] = src[c2 + 1][1];
                O[u][0] = __builtin_amdgcn_mfma_f32_32x32x16_bf16(va0[ks], bp, O[u][0], 0, 0, 0);
                O[u][1] = __builtin_amdgcn_mfma_f32_32x32x16_bf16(va1[ks], bp, O[u][1], 0, 0, 0);
                Ol[u]   = __builtin_amdgcn_mfma_f32_32x32x16_bf16(onesA,   bp, Ol[u],   0, 0, 0);
            }
    }

    // ---- combine the two kv-halves through LDS ----
    float* R    = (float*)&SM[0][0][0][0];    // [w4][u][64 d][32 q] = 32 KB
    float* Laux = R + 2 * 2 * 64 * 32;        // [w4][u][32 q]

    __syncthreads();                          // everyone done with tiles
    if (sp == 1) {
        #pragma unroll
        for (int u = 0; u < 2; ++u) {
            #pragma unroll
            for (int dt = 0; dt < 2; ++dt)
                #pragma unroll
                for (int r = 0; r < 16; ++r) {
                    const int d = (r & 3) + 8 * (r >> 2) + 4 * hf + 32 * dt;
                    R[(((w4 * 2 + u) * 64) + d) * 32 + lq] = O[u][dt][r];
                }
            if (hf == 0) Laux[(w4 * 2 + u) * 32 + lq] = Ol[u][0];
        }
    }
    __syncthreads();
    if (sp == 0) {
        #pragma unroll
        for (int u = 0; u < 2; ++u) {
            #pragma unroll
            for (int dt = 0; dt < 2; ++dt)
                #pragma unroll
                for (int r = 0; r < 16; ++r) {
                    const int d = (r & 3) + 8 * (r >> 2) + 4 * hf + 32 * dt;
                    O[u][dt][r] += R[(((w4 * 2 + u) * 64) + d) * 32 + lq];
                }
            const float lsum = Ol[u][0] + Laux[(w4 * 2 + u) * 32 + lq];
            const float linv = 1.0f / __shfl(lsum, lq);

            unsigned short* ob = ctx +
                ((size_t)b * N_SEQ + qbase + u * 32 + lq) * D_MODEL
                + h * DK + hf * 4;
            #pragma unroll
            for (int dt = 0; dt < 2; ++dt)
                #pragma unroll
                for (int c = 0; c < 4; ++c) {
                    unsigned int w2[2];
                    w2[0] = pack2(O[u][dt][4 * c + 0] * linv,
                                  O[u][dt][4 * c + 1] * linv);
                    w2[1] = pack2(O[u][dt][4 * c + 2] * linv,
                                  O[u][dt][4 * c + 3] * linv);
                    *(unsigned int*)(ob + dt * 32 + c * 8)     = w2[0];
                    *(unsigned int*)(ob + dt * 32 + c * 8 + 2) = w2[1];
                }
        }
    }
}

// ---------------------------------------------------------------------------
extern "C" void kernel_launch(void* const* d_in, const int* in_sizes, int n_in,
                              void* d_out, int out_size, void* d_ws, size_t ws_size,
                              hipStream_t stream)
{
    const float* x  = (const float*)d_in[0];
    const float* Wq = (const float*)d_in[1];
    const float* bq = (const float*)d_in[2];
    const float* Wk = (const float*)d_in[3];
    const float* bk = (const float*)d_in[4];
    const float* Wv = (const float*)d_in[5];
    const float* bv = (const float*)d_in[6];
    const float* Wo = (const float*)d_in[7];
    const float* bo = (const float*)d_in[8];
    float* out = (float*)d_out;

    const int M = in_sizes[0] / D_MODEL;        // 8192
    const size_t NX = (size_t)M * D_MODEL;
    const size_t NW = (size_t)D_MODEL * D_MODEL;

    unsigned short* xb  = (unsigned short*)d_ws;
    unsigned short* Wtq = xb + NX;
    unsigned short* Wtk = Wtq + NW;
    unsigned short* Wtv = Wtk + NW;
    unsigned short* Wto = Wtv + NW;
    unsigned short* Qb  = Wto + NW;
    unsigned short* Kb  = Qb + NX;
    unsigned short* Vtb = Kb + NX;
    unsigned short* ctx = Vtb + NX;

    convert_bf16<<<NX / (256 * 8), 256, 0, stream>>>(x, xb);
    transpose_all<<<dim3(16, 16, 4), dim3(32, 8), 0, stream>>>(
        Wq, Wk, Wv, Wo, Wtq, Wtk, Wtv, Wto);

    gemm_qkv<<<dim3(D_MODEL / 64, M / 128, 3), 256, 0, stream>>>(
        xb, Wtq, Wtk, Wtv, bq, bk, bv, Qb, Kb, Vtb);
    attn_mfma<<<512, 256, 0, stream>>>(Qb, Kb, Vtb, ctx);
    gemm_o<<<dim3(D_MODEL / 64, M / 64), 256, 0, stream>>>(ctx, Wto, bo, out);
}